// Round 1
// baseline (665.614 us; speedup 1.0000x reference)
//
#include <hip/hip_runtime.h>
#include <math.h>

#define NPTS 16384
#define DIN 13
#define HD 16
#define KNN 8
#define TJ 256

__device__ __forceinline__ float silu(float v) {
    return v / (1.0f + __expf(-v));
}

// ---------------- K1: encoder MLP -> x (N,16), sq (N) ----------------
__global__ __launch_bounds__(256) void k_encoder(
    const float* __restrict__ x_pfc,
    const float* __restrict__ W1, const float* __restrict__ b1,
    const float* __restrict__ W2, const float* __restrict__ b2,
    const float* __restrict__ W3, const float* __restrict__ b3,
    float* __restrict__ xo, float* __restrict__ sqo)
{
    __shared__ float sW1[DIN * 8];
    __shared__ float sb1[8];
    __shared__ float sW2[8 * 16];
    __shared__ float sb2[16];
    __shared__ float sW3[16 * 15];
    __shared__ float sb3[15];
    int t = threadIdx.x;
    for (int q = t; q < DIN * 8; q += 256) sW1[q] = W1[q];
    for (int q = t; q < 8; q += 256) sb1[q] = b1[q];
    for (int q = t; q < 8 * 16; q += 256) sW2[q] = W2[q];
    for (int q = t; q < 16; q += 256) sb2[q] = b2[q];
    for (int q = t; q < 16 * 15; q += 256) sW3[q] = W3[q];
    for (int q = t; q < 15; q += 256) sb3[q] = b3[q];
    __syncthreads();

    int i = blockIdx.x * 256 + t;
    float in[DIN];
#pragma unroll
    for (int d = 0; d < DIN; ++d) in[d] = x_pfc[i * DIN + d];

    float a1[8];
#pragma unroll
    for (int h = 0; h < 8; ++h) a1[h] = sb1[h];
#pragma unroll
    for (int d = 0; d < DIN; ++d) {
        float v = in[d];
#pragma unroll
        for (int h = 0; h < 8; ++h) a1[h] += v * sW1[d * 8 + h];
    }
#pragma unroll
    for (int h = 0; h < 8; ++h) a1[h] = silu(a1[h]);

    float a2[16];
#pragma unroll
    for (int h = 0; h < 16; ++h) a2[h] = sb2[h];
#pragma unroll
    for (int d = 0; d < 8; ++d) {
        float v = a1[d];
#pragma unroll
        for (int h = 0; h < 16; ++h) a2[h] += v * sW2[d * 16 + h];
    }
#pragma unroll
    for (int h = 0; h < 16; ++h) a2[h] = silu(a2[h]);

    float a3[15];
#pragma unroll
    for (int h = 0; h < 15; ++h) a3[h] = sb3[h];
#pragma unroll
    for (int d = 0; d < 16; ++d) {
        float v = a2[d];
#pragma unroll
        for (int h = 0; h < 15; ++h) a3[h] += v * sW3[d * 15 + h];
    }

    float xr[16];
#pragma unroll
    for (int h = 0; h < 15; ++h) xr[h] = a3[h];
    xr[15] = in[DIN - 1];

    float s = 0.0f;
#pragma unroll
    for (int d = 0; d < 16; ++d) s += xr[d] * xr[d];

#pragma unroll
    for (int d = 0; d < 16; ++d) xo[i * 16 + d] = xr[d];
    sqo[i] = s;
}

// ---------------- K2: exact KNN top-8 ----------------
// block = 512 threads = 8 waves; block handles 64 consecutive i's.
// Wave w scans j = w (mod 8) within each 256-j LDS tile, so all 64 lanes of a
// wave read the SAME x_j row (LDS broadcast, conflict-free).
__global__ __launch_bounds__(512) void k_knn(
    const float* __restrict__ x, const float* __restrict__ sq,
    int* __restrict__ knn_idx)
{
    __shared__ __align__(16) float xs[TJ * 16];
    __shared__ float sqs[TJ];
    __shared__ float md[64 * 64];   // [cand c][lane] lane-major -> conflict-free
    __shared__ int   mi[64 * 64];

    int t = threadIdx.x;
    int w = t >> 6;        // wave id 0..7 (j phase)
    int lane = t & 63;     // i within block
    int i = blockIdx.x * 64 + lane;

    float xi[16];
#pragma unroll
    for (int d = 0; d < 16; ++d) xi[d] = x[i * 16 + d];
    float sqi = sq[i];

    float dist[KNN];
    int id[KNN];
#pragma unroll
    for (int k = 0; k < KNN; ++k) { dist[k] = 3.4e38f; id[k] = -1; }

    for (int j0 = 0; j0 < NPTS; j0 += TJ) {
        __syncthreads();
        // cooperative tile load: 256x16 floats = 1024 float4, 512 threads
        for (int q = t; q < TJ * 16 / 4; q += 512) {
            ((float4*)xs)[q] = ((const float4*)(x + (size_t)j0 * 16))[q];
        }
        if (t < TJ) sqs[t] = sq[j0 + t];
        __syncthreads();

        for (int jj = w; jj < TJ; jj += 8) {
            const float* xr = &xs[jj * 16];
            float dot = 0.0f;
#pragma unroll
            for (int d = 0; d < 16; ++d) dot += xi[d] * xr[d];
            float d2 = sqi + sqs[jj] - 2.0f * dot;
            if (d2 < dist[KNN - 1]) {
                int j = j0 + jj;
                dist[KNN - 1] = d2; id[KNN - 1] = j;
#pragma unroll
                for (int k = KNN - 1; k > 0; --k) {
                    if (dist[k] < dist[k - 1]) {
                        float td = dist[k]; dist[k] = dist[k - 1]; dist[k - 1] = td;
                        int ti = id[k]; id[k] = id[k - 1]; id[k - 1] = ti;
                    }
                }
            }
        }
    }

    __syncthreads();
#pragma unroll
    for (int k = 0; k < KNN; ++k) {
        md[(w * KNN + k) * 64 + lane] = dist[k];
        mi[(w * KNN + k) * 64 + lane] = id[k];
    }
    __syncthreads();

    if (w == 0) {
        float fd[KNN];
        int fi[KNN];
#pragma unroll
        for (int k = 0; k < KNN; ++k) { fd[k] = 3.4e38f; fi[k] = -1; }
        for (int c = 0; c < 64; ++c) {
            float d2 = md[c * 64 + lane];
            int j = mi[c * 64 + lane];
            if (d2 < fd[KNN - 1]) {
                fd[KNN - 1] = d2; fi[KNN - 1] = j;
#pragma unroll
                for (int k = KNN - 1; k > 0; --k) {
                    if (fd[k] < fd[k - 1]) {
                        float td = fd[k]; fd[k] = fd[k - 1]; fd[k - 1] = td;
                        int ti = fi[k]; fi[k] = fi[k - 1]; fi[k - 1] = ti;
                    }
                }
            }
        }
#pragma unroll
        for (int k = 0; k < KNN; ++k) knn_idx[i * KNN + k] = fi[k];
    }
}

// ---------------- K3: edge conv + head MLP + output concat ----------------
__global__ __launch_bounds__(256) void k_head(
    const float* __restrict__ x, const int* __restrict__ knn_idx,
    const float* __restrict__ x_pfc,
    const float* __restrict__ We, const float* __restrict__ be,
    const float* __restrict__ Wf1, const float* __restrict__ bf1,
    const float* __restrict__ Wf2, const float* __restrict__ bf2,
    float* __restrict__ out)
{
    __shared__ float sWe[32 * 16];
    __shared__ float sbe[16];
    __shared__ float sWf1[16 * 32];
    __shared__ float sbf1[32];
    __shared__ float sWf2[32 * 16];
    __shared__ float sbf2[16];
    int t = threadIdx.x;
    for (int q = t; q < 32 * 16; q += 256) sWe[q] = We[q];
    for (int q = t; q < 16; q += 256) sbe[q] = be[q];
    for (int q = t; q < 16 * 32; q += 256) sWf1[q] = Wf1[q];
    for (int q = t; q < 32; q += 256) sbf1[q] = bf1[q];
    for (int q = t; q < 32 * 16; q += 256) sWf2[q] = Wf2[q];
    for (int q = t; q < 16; q += 256) sbf2[q] = bf2[q];
    __syncthreads();

    int i = blockIdx.x * 256 + t;
    float xi[16];
#pragma unroll
    for (int d = 0; d < 16; ++d) xi[d] = x[i * 16 + d];

    float feats[16];
#pragma unroll
    for (int h = 0; h < 16; ++h) feats[h] = 0.0f;

    for (int e = 0; e < KNN; ++e) {
        int j = knn_idx[i * KNN + e];
        float ein[32];
#pragma unroll
        for (int d = 0; d < 16; ++d) {
            float xj = x[j * 16 + d];
            ein[d] = xi[d];
            ein[16 + d] = xj - xi[d];
        }
        float acc[16];
#pragma unroll
        for (int h = 0; h < 16; ++h) acc[h] = sbe[h];
#pragma unroll
        for (int k = 0; k < 32; ++k) {
            float v = ein[k];
#pragma unroll
            for (int h = 0; h < 16; ++h) acc[h] += v * sWe[k * 16 + h];
        }
#pragma unroll
        for (int h = 0; h < 16; ++h) feats[h] += silu(acc[h]);
    }
#pragma unroll
    for (int h = 0; h < 16; ++h) feats[h] *= (1.0f / KNN);

    float f1[32];
#pragma unroll
    for (int h = 0; h < 32; ++h) f1[h] = sbf1[h];
#pragma unroll
    for (int k = 0; k < 16; ++k) {
        float v = feats[k];
#pragma unroll
        for (int h = 0; h < 32; ++h) f1[h] += v * sWf1[k * 32 + h];
    }
#pragma unroll
    for (int h = 0; h < 32; ++h) f1[h] = silu(f1[h]);

    float f2[16];
#pragma unroll
    for (int h = 0; h < 16; ++h) f2[h] = sbf2[h];
#pragma unroll
    for (int k = 0; k < 32; ++k) {
        float v = f1[k];
#pragma unroll
        for (int h = 0; h < 16; ++h) f2[h] += v * sWf2[k * 16 + h];
    }

#pragma unroll
    for (int h = 0; h < 16; ++h) out[(size_t)i * 29 + h] = f2[h];
#pragma unroll
    for (int d = 0; d < DIN; ++d) out[(size_t)i * 29 + 16 + d] = x_pfc[i * DIN + d];
}

extern "C" void kernel_launch(void* const* d_in, const int* in_sizes, int n_in,
                              void* d_out, int out_size, void* d_ws, size_t ws_size,
                              hipStream_t stream)
{
    const float* x_pfc = (const float*)d_in[0];
    const float* W1 = (const float*)d_in[1];
    const float* b1 = (const float*)d_in[2];
    const float* W2 = (const float*)d_in[3];
    const float* b2 = (const float*)d_in[4];
    const float* W3 = (const float*)d_in[5];
    const float* b3 = (const float*)d_in[6];
    const float* We = (const float*)d_in[7];
    const float* be = (const float*)d_in[8];
    const float* Wf1 = (const float*)d_in[9];
    const float* bf1 = (const float*)d_in[10];
    const float* Wf2 = (const float*)d_in[11];
    const float* bf2 = (const float*)d_in[12];
    float* out = (float*)d_out;

    float* xw = (float*)d_ws;               // N*16 floats
    float* sqw = xw + (size_t)NPTS * 16;    // N floats
    int* idxw = (int*)(sqw + NPTS);         // N*8 ints

    hipLaunchKernelGGL(k_encoder, dim3(NPTS / 256), dim3(256), 0, stream,
                       x_pfc, W1, b1, W2, b2, W3, b3, xw, sqw);
    hipLaunchKernelGGL(k_knn, dim3(NPTS / 64), dim3(512), 0, stream,
                       xw, sqw, idxw);
    hipLaunchKernelGGL(k_head, dim3(NPTS / 256), dim3(256), 0, stream,
                       xw, idxw, x_pfc, We, be, Wf1, bf1, Wf2, bf2, out);
}

// Round 2
// 534.674 us; speedup vs baseline: 1.2449x; 1.2449x over previous
//
#include <hip/hip_runtime.h>
#include <math.h>

#define NPTS 16384
#define DIN 13
#define KNN 8
#define WAVES_PER_BLK 16
#define JCHUNK (NPTS / WAVES_PER_BLK)   // 1024 j's per wave

__device__ __forceinline__ float silu(float v) {
    return v / (1.0f + __expf(-v));
}

// branchless insert of (v, j) into sorted ascending dist[8]/id[8].
// Self-predicating: if v >= dist[7] it is a no-op.
__device__ __forceinline__ void insert8(float v, int j, float* dist, int* id) {
    bool c[KNN];
#pragma unroll
    for (int k = 0; k < KNN; ++k) c[k] = v < dist[k];
#pragma unroll
    for (int k = KNN - 1; k >= 1; --k) {
        id[k] = c[k - 1] ? id[k - 1] : (c[k] ? j : id[k]);
        dist[k] = fminf(fmaxf(v, dist[k - 1]), dist[k]);  // med3
    }
    id[0] = c[0] ? j : id[0];
    dist[0] = fminf(v, dist[0]);
}

// ---------------- K1: encoder MLP -> x (N,16), sq (N) ----------------
__global__ __launch_bounds__(256) void k_encoder(
    const float* __restrict__ x_pfc,
    const float* __restrict__ W1, const float* __restrict__ b1,
    const float* __restrict__ W2, const float* __restrict__ b2,
    const float* __restrict__ W3, const float* __restrict__ b3,
    float* __restrict__ xo, float* __restrict__ sqo)
{
    __shared__ float sW1[DIN * 8];
    __shared__ float sb1[8];
    __shared__ float sW2[8 * 16];
    __shared__ float sb2[16];
    __shared__ float sW3[16 * 15];
    __shared__ float sb3[15];
    int t = threadIdx.x;
    for (int q = t; q < DIN * 8; q += 256) sW1[q] = W1[q];
    for (int q = t; q < 8; q += 256) sb1[q] = b1[q];
    for (int q = t; q < 8 * 16; q += 256) sW2[q] = W2[q];
    for (int q = t; q < 16; q += 256) sb2[q] = b2[q];
    for (int q = t; q < 16 * 15; q += 256) sW3[q] = W3[q];
    for (int q = t; q < 15; q += 256) sb3[q] = b3[q];
    __syncthreads();

    int i = blockIdx.x * 256 + t;
    float in[DIN];
#pragma unroll
    for (int d = 0; d < DIN; ++d) in[d] = x_pfc[i * DIN + d];

    float a1[8];
#pragma unroll
    for (int h = 0; h < 8; ++h) a1[h] = sb1[h];
#pragma unroll
    for (int d = 0; d < DIN; ++d) {
        float v = in[d];
#pragma unroll
        for (int h = 0; h < 8; ++h) a1[h] += v * sW1[d * 8 + h];
    }
#pragma unroll
    for (int h = 0; h < 8; ++h) a1[h] = silu(a1[h]);

    float a2[16];
#pragma unroll
    for (int h = 0; h < 16; ++h) a2[h] = sb2[h];
#pragma unroll
    for (int d = 0; d < 8; ++d) {
        float v = a1[d];
#pragma unroll
        for (int h = 0; h < 16; ++h) a2[h] += v * sW2[d * 16 + h];
    }
#pragma unroll
    for (int h = 0; h < 16; ++h) a2[h] = silu(a2[h]);

    float a3[15];
#pragma unroll
    for (int h = 0; h < 15; ++h) a3[h] = sb3[h];
#pragma unroll
    for (int d = 0; d < 16; ++d) {
        float v = a2[d];
#pragma unroll
        for (int h = 0; h < 15; ++h) a3[h] += v * sW3[d * 15 + h];
    }

    float xr[16];
#pragma unroll
    for (int h = 0; h < 15; ++h) xr[h] = a3[h];
    xr[15] = in[DIN - 1];

    float s = 0.0f;
#pragma unroll
    for (int d = 0; d < 16; ++d) s += xr[d] * xr[d];

#pragma unroll
    for (int d = 0; d < 16; ++d) xo[i * 16 + d] = xr[d];
    sqo[i] = s;
}

// ---------------- K2: exact KNN top-8, scalar-pipe j-rows ----------------
// block = 1024 threads = 16 waves handling the same 64 i's (one per lane).
// Wave w scans j in [w*1024, (w+1)*1024): j is wave-uniform -> x[j] row and
// sq[j] become s_load (SMEM pipe), freeing VALU+LDS. Ranking key
// v = sq[j] - 2*dot(xi,xj) (sqi dropped: order-equivalent per i).
__global__ __launch_bounds__(1024, 4) void k_knn(
    const float* __restrict__ x, const float* __restrict__ sq,
    int* __restrict__ knn_idx)
{
    __shared__ float md[WAVES_PER_BLK * KNN * 64];
    __shared__ int   mi[WAVES_PER_BLK * KNN * 64];

    int t = threadIdx.x;
    int w = t >> 6;
    int lane = t & 63;
    int i = blockIdx.x * 64 + lane;

    float xi[16];
    {
        const float4* xv = (const float4*)(x + (size_t)i * 16);
#pragma unroll
        for (int q = 0; q < 4; ++q) {
            float4 v = xv[q];
            xi[q * 4 + 0] = v.x; xi[q * 4 + 1] = v.y;
            xi[q * 4 + 2] = v.z; xi[q * 4 + 3] = v.w;
        }
    }

    float dist[KNN];
    int id[KNN];
#pragma unroll
    for (int k = 0; k < KNN; ++k) { dist[k] = 3.4e38f; id[k] = -1; }

    // wave-uniform j start (readfirstlane so the compiler proves uniformity)
    int jstart = __builtin_amdgcn_readfirstlane(w * JCHUNK);

    for (int jj = 0; jj < JCHUNK; jj += 2) {
        int j0 = jstart + jj;
        int j1 = j0 + 1;
        const float* r0 = x + (size_t)j0 * 16;
        const float* r1 = x + (size_t)j1 * 16;
        float sq0 = sq[j0];
        float sq1 = sq[j1];
        float a0[16], a1[16];
#pragma unroll
        for (int d = 0; d < 16; ++d) a0[d] = r0[d];
#pragma unroll
        for (int d = 0; d < 16; ++d) a1[d] = r1[d];

        float dot0 = 0.0f, dot1 = 0.0f;
#pragma unroll
        for (int d = 0; d < 16; ++d) dot0 = fmaf(xi[d], a0[d], dot0);
#pragma unroll
        for (int d = 0; d < 16; ++d) dot1 = fmaf(xi[d], a1[d], dot1);

        float v0 = fmaf(dot0, -2.0f, sq0);
        float v1 = fmaf(dot1, -2.0f, sq1);

        if (__any(v0 < dist[KNN - 1])) insert8(v0, j0, dist, id);
        if (__any(v1 < dist[KNN - 1])) insert8(v1, j1, dist, id);
    }

    // stage per-wave top-8 (lane-major: conflict-free)
#pragma unroll
    for (int k = 0; k < KNN; ++k) {
        md[(w * KNN + k) * 64 + lane] = dist[k];
        mi[(w * KNN + k) * 64 + lane] = id[k];
    }
    __syncthreads();

    if (w == 0) {
        float fd[KNN];
        int fi[KNN];
#pragma unroll
        for (int k = 0; k < KNN; ++k) { fd[k] = 3.4e38f; fi[k] = -1; }
        for (int c = 0; c < WAVES_PER_BLK * KNN; ++c) {
            float v = md[c * 64 + lane];
            int j = mi[c * 64 + lane];
            insert8(v, j, fd, fi);
        }
#pragma unroll
        for (int k = 0; k < KNN; ++k) knn_idx[i * KNN + k] = fi[k];
    }
}

// ---------------- K3: edge conv + head MLP + output concat ----------------
__global__ __launch_bounds__(256) void k_head(
    const float* __restrict__ x, const int* __restrict__ knn_idx,
    const float* __restrict__ x_pfc,
    const float* __restrict__ We, const float* __restrict__ be,
    const float* __restrict__ Wf1, const float* __restrict__ bf1,
    const float* __restrict__ Wf2, const float* __restrict__ bf2,
    float* __restrict__ out)
{
    __shared__ float sWe[32 * 16];
    __shared__ float sbe[16];
    __shared__ float sWf1[16 * 32];
    __shared__ float sbf1[32];
    __shared__ float sWf2[32 * 16];
    __shared__ float sbf2[16];
    int t = threadIdx.x;
    for (int q = t; q < 32 * 16; q += 256) sWe[q] = We[q];
    for (int q = t; q < 16; q += 256) sbe[q] = be[q];
    for (int q = t; q < 16 * 32; q += 256) sWf1[q] = Wf1[q];
    for (int q = t; q < 32; q += 256) sbf1[q] = bf1[q];
    for (int q = t; q < 32 * 16; q += 256) sWf2[q] = Wf2[q];
    for (int q = t; q < 16; q += 256) sbf2[q] = bf2[q];
    __syncthreads();

    int i = blockIdx.x * 256 + t;
    float xi[16];
#pragma unroll
    for (int d = 0; d < 16; ++d) xi[d] = x[i * 16 + d];

    float feats[16];
#pragma unroll
    for (int h = 0; h < 16; ++h) feats[h] = 0.0f;

    for (int e = 0; e < KNN; ++e) {
        int j = knn_idx[i * KNN + e];
        float ein[32];
#pragma unroll
        for (int d = 0; d < 16; ++d) {
            float xj = x[j * 16 + d];
            ein[d] = xi[d];
            ein[16 + d] = xj - xi[d];
        }
        float acc[16];
#pragma unroll
        for (int h = 0; h < 16; ++h) acc[h] = sbe[h];
#pragma unroll
        for (int k = 0; k < 32; ++k) {
            float v = ein[k];
#pragma unroll
            for (int h = 0; h < 16; ++h) acc[h] += v * sWe[k * 16 + h];
        }
#pragma unroll
        for (int h = 0; h < 16; ++h) feats[h] += silu(acc[h]);
    }
#pragma unroll
    for (int h = 0; h < 16; ++h) feats[h] *= (1.0f / KNN);

    float f1[32];
#pragma unroll
    for (int h = 0; h < 32; ++h) f1[h] = sbf1[h];
#pragma unroll
    for (int k = 0; k < 16; ++k) {
        float v = feats[k];
#pragma unroll
        for (int h = 0; h < 32; ++h) f1[h] += v * sWf1[k * 32 + h];
    }
#pragma unroll
    for (int h = 0; h < 32; ++h) f1[h] = silu(f1[h]);

    float f2[16];
#pragma unroll
    for (int h = 0; h < 16; ++h) f2[h] = sbf2[h];
#pragma unroll
    for (int k = 0; k < 32; ++k) {
        float v = f1[k];
#pragma unroll
        for (int h = 0; h < 16; ++h) f2[h] += v * sWf2[k * 16 + h];
    }

#pragma unroll
    for (int h = 0; h < 16; ++h) out[(size_t)i * 29 + h] = f2[h];
#pragma unroll
    for (int d = 0; d < DIN; ++d) out[(size_t)i * 29 + 16 + d] = x_pfc[i * DIN + d];
}

extern "C" void kernel_launch(void* const* d_in, const int* in_sizes, int n_in,
                              void* d_out, int out_size, void* d_ws, size_t ws_size,
                              hipStream_t stream)
{
    const float* x_pfc = (const float*)d_in[0];
    const float* W1 = (const float*)d_in[1];
    const float* b1 = (const float*)d_in[2];
    const float* W2 = (const float*)d_in[3];
    const float* b2 = (const float*)d_in[4];
    const float* W3 = (const float*)d_in[5];
    const float* b3 = (const float*)d_in[6];
    const float* We = (const float*)d_in[7];
    const float* be = (const float*)d_in[8];
    const float* Wf1 = (const float*)d_in[9];
    const float* bf1 = (const float*)d_in[10];
    const float* Wf2 = (const float*)d_in[11];
    const float* bf2 = (const float*)d_in[12];
    float* out = (float*)d_out;

    float* xw = (float*)d_ws;               // N*16 floats
    float* sqw = xw + (size_t)NPTS * 16;    // N floats
    int* idxw = (int*)(sqw + NPTS);         // N*8 ints

    hipLaunchKernelGGL(k_encoder, dim3(NPTS / 256), dim3(256), 0, stream,
                       x_pfc, W1, b1, W2, b2, W3, b3, xw, sqw);
    hipLaunchKernelGGL(k_knn, dim3(NPTS / 64), dim3(1024), 0, stream,
                       xw, sqw, idxw);
    hipLaunchKernelGGL(k_head, dim3(NPTS / 256), dim3(256), 0, stream,
                       xw, idxw, x_pfc, We, be, Wf1, bf1, Wf2, bf2, out);
}

// Round 3
// 493.438 us; speedup vs baseline: 1.3489x; 1.0836x over previous
//
#include <hip/hip_runtime.h>
#include <math.h>

#define NPTS 16384
#define DIN 13
#define KNN 8
#define WAVES_PER_BLK 16
#define JCHUNK (NPTS / WAVES_PER_BLK)   // 1024 j's per wave

__device__ __forceinline__ float silu(float v) {
    return v / (1.0f + __expf(-v));
}

// branchless values-only insert into sorted ascending dist[8]:
// 8 independent med3-class ops, no compares, no branches.
__device__ __forceinline__ void ins8v(float v, float* dist) {
#pragma unroll
    for (int k = KNN - 1; k >= 1; --k)
        dist[k] = fminf(fmaxf(v, dist[k - 1]), dist[k]);   // v_med3_f32
    dist[0] = fminf(v, dist[0]);
}

// the ranking key: v = sq[j] - 2*dot(xi,xj). MUST be bit-identical between
// pass 1 and pass 2 -> single function, fixed fmaf order.
__device__ __forceinline__ float keyval(const float* __restrict__ r,
                                        float sqv, const float* xi) {
    float dot = 0.0f;
#pragma unroll
    for (int d = 0; d < 16; ++d) dot = fmaf(xi[d], r[d], dot);
    return fmaf(dot, -2.0f, sqv);
}

// ---------------- K1: encoder MLP -> x (N,16), sq (N) ----------------
__global__ __launch_bounds__(256) void k_encoder(
    const float* __restrict__ x_pfc,
    const float* __restrict__ W1, const float* __restrict__ b1,
    const float* __restrict__ W2, const float* __restrict__ b2,
    const float* __restrict__ W3, const float* __restrict__ b3,
    float* __restrict__ xo, float* __restrict__ sqo)
{
    __shared__ float sW1[DIN * 8];
    __shared__ float sb1[8];
    __shared__ float sW2[8 * 16];
    __shared__ float sb2[16];
    __shared__ float sW3[16 * 15];
    __shared__ float sb3[15];
    int t = threadIdx.x;
    for (int q = t; q < DIN * 8; q += 256) sW1[q] = W1[q];
    for (int q = t; q < 8; q += 256) sb1[q] = b1[q];
    for (int q = t; q < 8 * 16; q += 256) sW2[q] = W2[q];
    for (int q = t; q < 16; q += 256) sb2[q] = b2[q];
    for (int q = t; q < 16 * 15; q += 256) sW3[q] = W3[q];
    for (int q = t; q < 15; q += 256) sb3[q] = b3[q];
    __syncthreads();

    int i = blockIdx.x * 256 + t;
    float in[DIN];
#pragma unroll
    for (int d = 0; d < DIN; ++d) in[d] = x_pfc[i * DIN + d];

    float a1[8];
#pragma unroll
    for (int h = 0; h < 8; ++h) a1[h] = sb1[h];
#pragma unroll
    for (int d = 0; d < DIN; ++d) {
        float v = in[d];
#pragma unroll
        for (int h = 0; h < 8; ++h) a1[h] += v * sW1[d * 8 + h];
    }
#pragma unroll
    for (int h = 0; h < 8; ++h) a1[h] = silu(a1[h]);

    float a2[16];
#pragma unroll
    for (int h = 0; h < 16; ++h) a2[h] = sb2[h];
#pragma unroll
    for (int d = 0; d < 8; ++d) {
        float v = a1[d];
#pragma unroll
        for (int h = 0; h < 16; ++h) a2[h] += v * sW2[d * 16 + h];
    }
#pragma unroll
    for (int h = 0; h < 16; ++h) a2[h] = silu(a2[h]);

    float a3[15];
#pragma unroll
    for (int h = 0; h < 15; ++h) a3[h] = sb3[h];
#pragma unroll
    for (int d = 0; d < 16; ++d) {
        float v = a2[d];
#pragma unroll
        for (int h = 0; h < 15; ++h) a3[h] += v * sW3[d * 15 + h];
    }

    float xr[16];
#pragma unroll
    for (int h = 0; h < 15; ++h) xr[h] = a3[h];
    xr[15] = in[DIN - 1];

    float s = 0.0f;
#pragma unroll
    for (int d = 0; d < 16; ++d) s += xr[d] * xr[d];

#pragma unroll
    for (int d = 0; d < 16; ++d) xo[i * 16 + d] = xr[d];
    sqo[i] = s;
}

// ---------------- K2: exact KNN top-8, two-pass (values then ids) --------
// block = 1024 threads = 16 waves over the same 64 i's (one per lane).
// Pass 1: branchless values-only top-8 per wave over its 1024-j chunk.
// Merge: wave 0 -> exact global 8th-smallest key per i.
// Pass 2: rescan, v <= kth (bit-identical arithmetic) -> push id. True-hit
// rate ~8/16384 per lane, so the per-wave branch actually skips.
__global__ __launch_bounds__(1024, 4) void k_knn(
    const float* __restrict__ x, const float* __restrict__ sq,
    int* __restrict__ knn_idx)
{
    __shared__ float md[WAVES_PER_BLK * KNN * 64];   // 32 KB, lane-major
    __shared__ float kths[64];
    __shared__ int cnt[64];
    __shared__ int ids[64 * KNN];

    int t = threadIdx.x;
    int w = t >> 6;
    int lane = t & 63;
    int i = blockIdx.x * 64 + lane;

    float xi[16];
    {
        const float4* xv = (const float4*)(x + (size_t)i * 16);
#pragma unroll
        for (int q = 0; q < 4; ++q) {
            float4 v = xv[q];
            xi[q * 4 + 0] = v.x; xi[q * 4 + 1] = v.y;
            xi[q * 4 + 2] = v.z; xi[q * 4 + 3] = v.w;
        }
    }

    float dist[KNN];
#pragma unroll
    for (int k = 0; k < KNN; ++k) dist[k] = 3.4e38f;

    int jstart = __builtin_amdgcn_readfirstlane(w * JCHUNK);

    // ---- pass 1: branchless values-only scan, 4-way j unroll ----
    for (int jj = 0; jj < JCHUNK; jj += 4) {
        int j0 = jstart + jj;
        const float* r0 = x + (size_t)j0 * 16;
        const float* r1 = r0 + 16;
        const float* r2 = r0 + 32;
        const float* r3 = r0 + 48;
        float s0 = sq[j0], s1 = sq[j0 + 1], s2 = sq[j0 + 2], s3 = sq[j0 + 3];
        float v0 = keyval(r0, s0, xi);
        float v1 = keyval(r1, s1, xi);
        float v2 = keyval(r2, s2, xi);
        float v3 = keyval(r3, s3, xi);
        ins8v(v0, dist);
        ins8v(v1, dist);
        ins8v(v2, dist);
        ins8v(v3, dist);
    }

    // stage per-wave top-8 values (lane-major: conflict-free)
#pragma unroll
    for (int k = 0; k < KNN; ++k)
        md[(w * KNN + k) * 64 + lane] = dist[k];
    // init pass-2 state
    if (t < 64) cnt[t] = 0;
    if (t < 64 * KNN) ids[t] = blockIdx.x * 64 + (t >> 3);  // benign default
    __syncthreads();

    // ---- merge: exact global 8th-smallest value per i ----
    if (w == 0) {
        float fd[KNN];
#pragma unroll
        for (int k = 0; k < KNN; ++k) fd[k] = 3.4e38f;
        for (int c = 0; c < WAVES_PER_BLK * KNN; ++c)
            ins8v(md[c * 64 + lane], fd);
        kths[lane] = fd[KNN - 1];
    }
    __syncthreads();

    float kth = kths[lane];

    // ---- pass 2: collect ids of hits (v <= kth), rare slow path ----
    for (int jj = 0; jj < JCHUNK; jj += 4) {
        int j0 = jstart + jj;
        const float* r0 = x + (size_t)j0 * 16;
        const float* r1 = r0 + 16;
        const float* r2 = r0 + 32;
        const float* r3 = r0 + 48;
        float s0 = sq[j0], s1 = sq[j0 + 1], s2 = sq[j0 + 2], s3 = sq[j0 + 3];
        float v0 = keyval(r0, s0, xi);
        float v1 = keyval(r1, s1, xi);
        float v2 = keyval(r2, s2, xi);
        float v3 = keyval(r3, s3, xi);
        bool h0 = v0 <= kth, h1 = v1 <= kth, h2 = v2 <= kth, h3 = v3 <= kth;
        if (__any(h0) | __any(h1) | __any(h2) | __any(h3)) {
            if (h0) { int s = atomicAdd(&cnt[lane], 1); if (s < KNN) ids[lane * KNN + s] = j0; }
            if (h1) { int s = atomicAdd(&cnt[lane], 1); if (s < KNN) ids[lane * KNN + s] = j0 + 1; }
            if (h2) { int s = atomicAdd(&cnt[lane], 1); if (s < KNN) ids[lane * KNN + s] = j0 + 2; }
            if (h3) { int s = atomicAdd(&cnt[lane], 1); if (s < KNN) ids[lane * KNN + s] = j0 + 3; }
        }
    }
    __syncthreads();

    if (w == 0) {
#pragma unroll
        for (int k = 0; k < KNN; ++k)
            knn_idx[i * KNN + k] = ids[lane * KNN + k];
    }
}

// ---------------- K3: edge conv + head MLP + output concat ----------------
__global__ __launch_bounds__(256) void k_head(
    const float* __restrict__ x, const int* __restrict__ knn_idx,
    const float* __restrict__ x_pfc,
    const float* __restrict__ We, const float* __restrict__ be,
    const float* __restrict__ Wf1, const float* __restrict__ bf1,
    const float* __restrict__ Wf2, const float* __restrict__ bf2,
    float* __restrict__ out)
{
    __shared__ float sWe[32 * 16];
    __shared__ float sbe[16];
    __shared__ float sWf1[16 * 32];
    __shared__ float sbf1[32];
    __shared__ float sWf2[32 * 16];
    __shared__ float sbf2[16];
    int t = threadIdx.x;
    for (int q = t; q < 32 * 16; q += 256) sWe[q] = We[q];
    for (int q = t; q < 16; q += 256) sbe[q] = be[q];
    for (int q = t; q < 16 * 32; q += 256) sWf1[q] = Wf1[q];
    for (int q = t; q < 32; q += 256) sbf1[q] = bf1[q];
    for (int q = t; q < 32 * 16; q += 256) sWf2[q] = Wf2[q];
    for (int q = t; q < 16; q += 256) sbf2[q] = bf2[q];
    __syncthreads();

    int i = blockIdx.x * 256 + t;
    float xi[16];
#pragma unroll
    for (int d = 0; d < 16; ++d) xi[d] = x[i * 16 + d];

    // hoist the x_i half of the edge MLP out of the neighbor loop:
    // acc = be + xi @ We[0:16] + (xj-xi) @ We[16:32]
    float accb[16];
#pragma unroll
    for (int h = 0; h < 16; ++h) accb[h] = sbe[h];
#pragma unroll
    for (int d = 0; d < 16; ++d) {
        float v = xi[d];
#pragma unroll
        for (int h = 0; h < 16; ++h) accb[h] += v * sWe[d * 16 + h];
    }

    float feats[16];
#pragma unroll
    for (int h = 0; h < 16; ++h) feats[h] = 0.0f;

    for (int e = 0; e < KNN; ++e) {
        int j = knn_idx[i * KNN + e];
        float xd[16];
        const float4* xjv = (const float4*)(x + (size_t)j * 16);
#pragma unroll
        for (int q = 0; q < 4; ++q) {
            float4 v = xjv[q];
            xd[q * 4 + 0] = v.x - xi[q * 4 + 0];
            xd[q * 4 + 1] = v.y - xi[q * 4 + 1];
            xd[q * 4 + 2] = v.z - xi[q * 4 + 2];
            xd[q * 4 + 3] = v.w - xi[q * 4 + 3];
        }
        float acc[16];
#pragma unroll
        for (int h = 0; h < 16; ++h) acc[h] = accb[h];
#pragma unroll
        for (int d = 0; d < 16; ++d) {
            float v = xd[d];
#pragma unroll
            for (int h = 0; h < 16; ++h) acc[h] += v * sWe[(16 + d) * 16 + h];
        }
#pragma unroll
        for (int h = 0; h < 16; ++h) feats[h] += silu(acc[h]);
    }
#pragma unroll
    for (int h = 0; h < 16; ++h) feats[h] *= (1.0f / KNN);

    float f1[32];
#pragma unroll
    for (int h = 0; h < 32; ++h) f1[h] = sbf1[h];
#pragma unroll
    for (int k = 0; k < 16; ++k) {
        float v = feats[k];
#pragma unroll
        for (int h = 0; h < 32; ++h) f1[h] += v * sWf1[k * 32 + h];
    }
#pragma unroll
    for (int h = 0; h < 32; ++h) f1[h] = silu(f1[h]);

    float f2[16];
#pragma unroll
    for (int h = 0; h < 16; ++h) f2[h] = sbf2[h];
#pragma unroll
    for (int k = 0; k < 32; ++k) {
        float v = f1[k];
#pragma unroll
        for (int h = 0; h < 16; ++h) f2[h] += v * sWf2[k * 16 + h];
    }

#pragma unroll
    for (int h = 0; h < 16; ++h) out[(size_t)i * 29 + h] = f2[h];
#pragma unroll
    for (int d = 0; d < DIN; ++d) out[(size_t)i * 29 + 16 + d] = x_pfc[i * DIN + d];
}

extern "C" void kernel_launch(void* const* d_in, const int* in_sizes, int n_in,
                              void* d_out, int out_size, void* d_ws, size_t ws_size,
                              hipStream_t stream)
{
    const float* x_pfc = (const float*)d_in[0];
    const float* W1 = (const float*)d_in[1];
    const float* b1 = (const float*)d_in[2];
    const float* W2 = (const float*)d_in[3];
    const float* b2 = (const float*)d_in[4];
    const float* W3 = (const float*)d_in[5];
    const float* b3 = (const float*)d_in[6];
    const float* We = (const float*)d_in[7];
    const float* be = (const float*)d_in[8];
    const float* Wf1 = (const float*)d_in[9];
    const float* bf1 = (const float*)d_in[10];
    const float* Wf2 = (const float*)d_in[11];
    const float* bf2 = (const float*)d_in[12];
    float* out = (float*)d_out;

    float* xw = (float*)d_ws;               // N*16 floats
    float* sqw = xw + (size_t)NPTS * 16;    // N floats
    int* idxw = (int*)(sqw + NPTS);         // N*8 ints

    hipLaunchKernelGGL(k_encoder, dim3(NPTS / 256), dim3(256), 0, stream,
                       x_pfc, W1, b1, W2, b2, W3, b3, xw, sqw);
    hipLaunchKernelGGL(k_knn, dim3(NPTS / 64), dim3(1024), 0, stream,
                       xw, sqw, idxw);
    hipLaunchKernelGGL(k_head, dim3(NPTS / 256), dim3(256), 0, stream,
                       xw, idxw, x_pfc, We, be, Wf1, bf1, Wf2, bf2, out);
}